// Round 3
// baseline (266.661 us; speedup 1.0000x reference)
//
#include <hip/hip_runtime.h>
#include <hip/hip_cooperative_groups.h>

namespace cg = cooperative_groups;

#define T_ 500
#define R_ 50
#define NS_ 1000
#define H1_ 32
#define H2_ 16
#define NEG_ 0.2f

__device__ __forceinline__ float lrelu(float x) { return x >= 0.f ? x : NEG_ * x; }

// One cooperative kernel for the whole logits chain. Grid = 500 blocks x 256 thr.
// S1: y1[t][32]  (x @ g1w)              -> gsync
// S2: h1 = lrelu(bn(adj@y1+b)); y2=h1@g2w -> gsync
// S3: xfrow = lrelu(bn(adj@y2+b2))  [kept in LDS, block t == split s]
// S4: part1[s][j] = xfrow @ aw rows      -> gsync
// S5: logits[r][j] = sum_s part1[s][j] + dloc[r]@av[:,j]
__global__ __launch_bounds__(256) void chain(const float* __restrict__ state,
                                             const float* __restrict__ dloc,
                                             const float* __restrict__ noise,
                                             const float* __restrict__ payoff,
                                             const float* __restrict__ adj,
                                             const float* __restrict__ g1w,
                                             const float* __restrict__ g1b,
                                             const float* __restrict__ g2w,
                                             const float* __restrict__ g2b,
                                             const float* __restrict__ gamma,
                                             const float* __restrict__ beta,
                                             const float* __restrict__ aw,
                                             const float* __restrict__ av,
                                             float* __restrict__ y1,
                                             float* __restrict__ y2,
                                             float* __restrict__ part1,
                                             float* __restrict__ logits) {
    cg::grid_group grid = cg::this_grid();
    __shared__ float sm[1024];
    const int b = blockIdx.x, tid = threadIdx.x;

    // ---- S1: y1[b][c] = x[b] @ g1w ----
    {
        float* xs  = sm;        // 504
        float* red = sm + 512;  // 8*32
        for (int u = tid; u < T_; u += 256) xs[2 + u] = payoff[b * T_ + u];
        if (tid == 0) {
            xs[0] = state[2 * b];   xs[1] = state[2 * b + 1];
            xs[502] = noise[2 * b]; xs[503] = noise[2 * b + 1];
        }
        __syncthreads();
        int c = tid & 31, kg = tid >> 5;
        float acc = 0.f;
        for (int f = kg; f < 504; f += 8) acc += xs[f] * g1w[f * H1_ + c];
        red[kg * 32 + c] = acc;
        __syncthreads();
        if (tid < H1_) {
            float a = 0.f;
#pragma unroll
            for (int s = 0; s < 8; ++s) a += red[s * 32 + tid];
            y1[b * H1_ + tid] = a;
        }
    }
    grid.sync();

    // ---- S2: h1row = lrelu(bn(adj[b]@y1 + b1)); y2[b] = h1row @ g2w ----
    {
        float* arow  = sm;        // 500 (kept for S3)
        float* red   = sm + 512;  // 256
        float* h1row = sm + 768;  // 32
        for (int u = tid; u < T_; u += 256) arow[u] = adj[b * T_ + u];
        __syncthreads();
        int c = tid & 31, kg = tid >> 5;
        float acc = 0.f;
        for (int u = kg; u < T_; u += 8) acc += arow[u] * y1[u * H1_ + c];
        red[kg * 32 + c] = acc;
        __syncthreads();
        if (tid < H1_) {
            float a = 0.f;
#pragma unroll
            for (int s = 0; s < 8; ++s) a += red[s * 32 + tid];
            h1row[tid] = lrelu((a + g1b[tid]) * gamma[b] + beta[b]);
        }
        __syncthreads();
        if (tid < H2_) {
            float a = 0.f;
#pragma unroll
            for (int cc = 0; cc < H1_; ++cc) a += h1row[cc] * g2w[cc * H2_ + tid];
            y2[b * H2_ + tid] = a;
        }
    }
    grid.sync();

    // ---- S3: xfrow[c2] = lrelu(bn(adj[b]@y2 + b2))  (arow still in LDS) ----
    {
        float* arow = sm;         // reused from S2
        float* red  = sm + 512;   // 16*16
        float* xfr  = sm + 992;   // 16
        int c2 = tid & 15, kg = tid >> 4;
        float acc = 0.f;
        for (int u = kg; u < T_; u += 16) acc += arow[u] * y2[u * H2_ + c2];
        red[kg * 16 + c2] = acc;
        __syncthreads();
        if (tid < H2_) {
            float a = 0.f;
#pragma unroll
            for (int s = 0; s < 16; ++s) a += red[s * 16 + tid];
            xfr[tid] = lrelu((a + g2b[tid]) * gamma[b] + beta[b]);
        }
        __syncthreads();

        // ---- S4 (no grid sync needed): part1[b][j] = xfrow @ aw[b*16 .. b*16+16) ----
        float acc0 = 0.f, acc1 = 0.f;
#pragma unroll
        for (int c = 0; c < H2_; ++c) {
            float xv = xfr[c];
            const float* awr = aw + (b * H2_ + c) * T_;
            acc0 += xv * awr[tid];
            if (tid < T_ - 256) acc1 += xv * awr[256 + tid];
        }
        part1[b * T_ + tid] = acc0;
        if (tid < T_ - 256) part1[b * T_ + 256 + tid] = acc1;
    }
    grid.sync();

    // ---- S5: logits[r][j] = sum_s part1[s][j] + dloc[r] @ av[:,j] ----
    {
        int r = b % R_, jc = b / R_;  // jc in [0,10): j-range [jc*50, jc*50+50)
        float* drow = sm;             // 500
        float* red  = sm + 512;       // 5*50
        for (int u = tid; u < T_; u += 256) drow[u] = dloc[r * T_ + u];
        __syncthreads();
        if (tid < 250) {
            int tg = tid / 50, jj = tid % 50;
            int j = jc * 50 + jj;
            float acc = 0.f;
            for (int t = tg; t < T_; t += 5)
                acc += drow[t] * av[t * T_ + j] + part1[t * T_ + j];
            red[tg * 50 + jj] = acc;
        }
        __syncthreads();
        if (tid < 50) {
            int j = jc * 50 + tid;
            float a = 0.f;
#pragma unroll
            for (int tg = 0; tg < 5; ++tg) a += red[tg * 50 + tid];
            logits[r * T_ + j] = a;
        }
    }
}

// One wave per softmax row, float4 loads/stores (row = 500 floats = 125 float4).
__global__ __launch_bounds__(256) void k7_softmax(const float4* __restrict__ gu,
                                                  const float4* __restrict__ logits,
                                                  float4* __restrict__ out) {
    int wave = threadIdx.x >> 6;
    int lane = threadIdx.x & 63;
    int row = blockIdx.x * 4 + wave;  // < 50000
    int r = row % R_;
    const float4* grow = gu + row * 125;
    const float4* lrow = logits + r * 125;
    bool has1 = lane < 61;

    float v[8];
    float4 g0 = grow[lane];
    float4 l0 = lrow[lane];
    v[0] = l0.x - __logf(-__logf(g0.x));
    v[1] = l0.y - __logf(-__logf(g0.y));
    v[2] = l0.z - __logf(-__logf(g0.z));
    v[3] = l0.w - __logf(-__logf(g0.w));
    if (has1) {
        float4 g1 = grow[64 + lane];
        float4 l1 = lrow[64 + lane];
        v[4] = l1.x - __logf(-__logf(g1.x));
        v[5] = l1.y - __logf(-__logf(g1.y));
        v[6] = l1.z - __logf(-__logf(g1.z));
        v[7] = l1.w - __logf(-__logf(g1.w));
    } else {
        v[4] = v[5] = v[6] = v[7] = -1e30f;
    }
    float m = fmaxf(fmaxf(fmaxf(v[0], v[1]), fmaxf(v[2], v[3])),
                    fmaxf(fmaxf(v[4], v[5]), fmaxf(v[6], v[7])));
#pragma unroll
    for (int off = 32; off > 0; off >>= 1) m = fmaxf(m, __shfl_xor(m, off));

    float ssum = 0.f;
#pragma unroll
    for (int i = 0; i < 8; ++i) {
        v[i] = (i < 4 || has1) ? __expf(v[i] - m) : 0.f;
        ssum += v[i];
    }
#pragma unroll
    for (int off = 32; off > 0; off >>= 1) ssum += __shfl_xor(ssum, off);
    float inv = 1.f / ssum;

    float4* orow = out + row * 125;
    float4 o0 = {v[0] * inv, v[1] * inv, v[2] * inv, v[3] * inv};
    orow[lane] = o0;
    if (has1) {
        float4 o1 = {v[4] * inv, v[5] * inv, v[6] * inv, v[7] * inv};
        orow[64 + lane] = o1;
    }
}

extern "C" void kernel_launch(void* const* d_in, const int* in_sizes, int n_in,
                              void* d_out, int out_size, void* d_ws, size_t ws_size,
                              hipStream_t stream) {
    const float* state  = (const float*)d_in[0];
    const float* dloc   = (const float*)d_in[1];
    const float* noise  = (const float*)d_in[2];
    const float* gu     = (const float*)d_in[3];
    const float* payoff = (const float*)d_in[4];
    const float* adj    = (const float*)d_in[5];
    const float* g1w    = (const float*)d_in[6];
    const float* g1b    = (const float*)d_in[7];
    const float* g2w    = (const float*)d_in[8];
    const float* g2b    = (const float*)d_in[9];
    const float* gamma  = (const float*)d_in[10];
    const float* beta   = (const float*)d_in[11];
    const float* aw     = (const float*)d_in[12];
    const float* av     = (const float*)d_in[13];
    float* out = (float*)d_out;

    float* ws     = (float*)d_ws;
    float* y1     = ws;           // 16000
    float* y2     = ws + 16000;   // 8000
    float* part1  = ws + 24000;   // 500*500 = 250000
    float* logits = ws + 274000;  // 25000  (total 299000 floats = 1.20 MB)

    void* cargs[] = {
        (void*)&state, (void*)&dloc, (void*)&noise, (void*)&payoff, (void*)&adj,
        (void*)&g1w, (void*)&g1b, (void*)&g2w, (void*)&g2b, (void*)&gamma,
        (void*)&beta, (void*)&aw, (void*)&av,
        (void*)&y1, (void*)&y2, (void*)&part1, (void*)&logits,
    };
    hipLaunchCooperativeKernel((void*)chain, dim3(T_), dim3(256), cargs, 0, stream);

    k7_softmax<<<(NS_ * R_) / 4, 256, 0, stream>>>(
        (const float4*)gu, (const float4*)logits, (float4*)out);
}

// Round 4
// 73.526 us; speedup vs baseline: 3.6268x; 3.6268x over previous
//
#include <hip/hip_runtime.h>

#define T_ 500
#define R_ 50
#define NS_ 1000
#define H1_ 32
#define H2_ 16
#define NEG_ 0.2f

__device__ __forceinline__ float lrelu(float x) { return x >= 0.f ? x : NEG_ * x; }

// One block per t: y1[t][c] = sum_f x[t][f] * gc1_w[f][c],  x=[state(2)|payoff row(500)|noise(2)]
__global__ __launch_bounds__(256) void k1_xw(const float* __restrict__ state,
                                             const float* __restrict__ payoff,
                                             const float* __restrict__ noise,
                                             const float* __restrict__ w,
                                             float* __restrict__ y1) {
    __shared__ float xs[504];
    __shared__ float red[8][H1_];
    int t = blockIdx.x, tid = threadIdx.x;
    for (int u = tid; u < T_; u += 256) xs[2 + u] = payoff[t * T_ + u];
    if (tid == 0) {
        xs[0] = state[t * 2];     xs[1] = state[t * 2 + 1];
        xs[502] = noise[t * 2];   xs[503] = noise[t * 2 + 1];
    }
    __syncthreads();
    int c = tid & 31, kg = tid >> 5;   // 8 k-groups x 32 channels
    float acc = 0.f;
#pragma unroll 7
    for (int f = kg; f < 504; f += 8) acc += xs[f] * w[f * H1_ + c];
    red[kg][c] = acc;
    __syncthreads();
    if (tid < H1_) {
        float a = 0.f;
#pragma unroll
        for (int s = 0; s < 8; ++s) a += red[s][tid];
        y1[t * H1_ + tid] = a;
    }
}

// One block per t: h1row = lrelu(bn(adj[t]@y1 + b)); y2[t][c2] = h1row @ g2w
__global__ __launch_bounds__(256) void k2_adj_fused(const float* __restrict__ adj,
                                                    const float* __restrict__ y1,
                                                    const float* __restrict__ b,
                                                    const float* __restrict__ gamma,
                                                    const float* __restrict__ beta,
                                                    const float* __restrict__ w2,
                                                    float* __restrict__ y2) {
    __shared__ float arow[T_];
    __shared__ float red[8][H1_];
    __shared__ float h1row[H1_];
    int t = blockIdx.x, tid = threadIdx.x;
    for (int u = tid; u < T_; u += 256) arow[u] = adj[t * T_ + u];
    __syncthreads();
    int c = tid & 31, kg = tid >> 5;
    float acc = 0.f;
#pragma unroll 4
    for (int u = kg; u < T_; u += 8) acc += arow[u] * y1[u * H1_ + c];
    red[kg][c] = acc;
    __syncthreads();
    if (tid < H1_) {
        float a = 0.f;
#pragma unroll
        for (int s = 0; s < 8; ++s) a += red[s][tid];
        h1row[tid] = lrelu((a + b[tid]) * gamma[t] + beta[t]);
    }
    __syncthreads();
    if (tid < H2_) {
        float a = 0.f;
#pragma unroll
        for (int cc = 0; cc < H1_; ++cc) a += h1row[cc] * w2[cc * H2_ + tid];
        y2[t * H2_ + tid] = a;
    }
}

// One block per t: xfrow = lrelu(bn(adj[t]@y2 + b2)); part1[t][j] = xfrow @ aw[t*16..t*16+16)
__global__ __launch_bounds__(256) void k3_adj2_aw(const float* __restrict__ adj,
                                                  const float* __restrict__ y2,
                                                  const float* __restrict__ b2,
                                                  const float* __restrict__ gamma,
                                                  const float* __restrict__ beta,
                                                  const float* __restrict__ aw,
                                                  float* __restrict__ part1) {
    __shared__ float arow[T_];
    __shared__ float red[16][H2_];
    __shared__ float xfr[H2_];
    int t = blockIdx.x, tid = threadIdx.x;
    for (int u = tid; u < T_; u += 256) arow[u] = adj[t * T_ + u];
    __syncthreads();
    int c2 = tid & 15, kg = tid >> 4;  // 16 k-groups x 16 channels
    float acc = 0.f;
#pragma unroll 4
    for (int u = kg; u < T_; u += 16) acc += arow[u] * y2[u * H2_ + c2];
    red[kg][c2] = acc;
    __syncthreads();
    if (tid < H2_) {
        float a = 0.f;
#pragma unroll
        for (int s = 0; s < 16; ++s) a += red[s][tid];
        xfr[tid] = lrelu((a + b2[tid]) * gamma[t] + beta[t]);
    }
    __syncthreads();
    float acc0 = 0.f, acc1 = 0.f;
#pragma unroll
    for (int c = 0; c < H2_; ++c) {
        float xv = xfr[c];
        const float* awr = aw + (t * H2_ + c) * T_;
        acc0 += xv * awr[tid];
        if (tid < T_ - 256) acc1 += xv * awr[256 + tid];
    }
    part1[t * T_ + tid] = acc0;
    if (tid < T_ - 256) part1[t * T_ + 256 + tid] = acc1;
}

// Block (r, jb*4+q... flattened y = q*2+jb): partial logits over t-quarter q, j-half jb.
// part2[q][r*T+j] = sum_{t in q} dloc[r][t]*av[t][j] + part1[t][j]
__global__ __launch_bounds__(256) void k4_logits_part(const float* __restrict__ dloc,
                                                      const float* __restrict__ av,
                                                      const float* __restrict__ part1,
                                                      float* __restrict__ part2) {
    int r = blockIdx.x;
    int jb = blockIdx.y & 1, q = blockIdx.y >> 1;
    __shared__ float drow[125];
    int tid = threadIdx.x;
    int t0 = q * 125;
    if (tid < 125) drow[tid] = dloc[r * T_ + t0 + tid];
    __syncthreads();
    if (tid >= 250) return;
    int j = jb * 250 + tid;
    float acc = 0.f;
#pragma unroll 5
    for (int i = 0; i < 125; ++i) {
        int t = t0 + i;
        acc += drow[i] * av[t * T_ + j] + part1[t * T_ + j];
    }
    part2[q * (R_ * T_) + r * T_ + j] = acc;
}

// logits[x] = sum_q part2[q][x]
__global__ __launch_bounds__(256) void k4_reduce(const float* __restrict__ part2,
                                                 float* __restrict__ logits) {
    int gid = blockIdx.x * 256 + threadIdx.x;
    if (gid >= R_ * T_) return;
    logits[gid] = part2[gid] + part2[R_ * T_ + gid] +
                  part2[2 * R_ * T_ + gid] + part2[3 * R_ * T_ + gid];
}

// One wave per softmax row, float4 loads/stores (row = 500 floats = 125 float4).
__global__ __launch_bounds__(256) void k7_softmax(const float4* __restrict__ gu,
                                                  const float4* __restrict__ logits,
                                                  float4* __restrict__ out) {
    int wave = threadIdx.x >> 6;
    int lane = threadIdx.x & 63;
    int row = blockIdx.x * 4 + wave;  // < 50000
    int r = row % R_;
    const float4* grow = gu + row * 125;
    const float4* lrow = logits + r * 125;
    bool has1 = lane < 61;

    float v[8];
    float4 g0 = grow[lane];
    float4 l0 = lrow[lane];
    v[0] = l0.x - __logf(-__logf(g0.x));
    v[1] = l0.y - __logf(-__logf(g0.y));
    v[2] = l0.z - __logf(-__logf(g0.z));
    v[3] = l0.w - __logf(-__logf(g0.w));
    if (has1) {
        float4 g1 = grow[64 + lane];
        float4 l1 = lrow[64 + lane];
        v[4] = l1.x - __logf(-__logf(g1.x));
        v[5] = l1.y - __logf(-__logf(g1.y));
        v[6] = l1.z - __logf(-__logf(g1.z));
        v[7] = l1.w - __logf(-__logf(g1.w));
    } else {
        v[4] = v[5] = v[6] = v[7] = -1e30f;
    }
    float m = fmaxf(fmaxf(fmaxf(v[0], v[1]), fmaxf(v[2], v[3])),
                    fmaxf(fmaxf(v[4], v[5]), fmaxf(v[6], v[7])));
#pragma unroll
    for (int off = 32; off > 0; off >>= 1) m = fmaxf(m, __shfl_xor(m, off));

    float ssum = 0.f;
#pragma unroll
    for (int i = 0; i < 8; ++i) {
        v[i] = (i < 4 || has1) ? __expf(v[i] - m) : 0.f;
        ssum += v[i];
    }
#pragma unroll
    for (int off = 32; off > 0; off >>= 1) ssum += __shfl_xor(ssum, off);
    float inv = 1.f / ssum;

    float4* orow = out + row * 125;
    float4 o0 = {v[0] * inv, v[1] * inv, v[2] * inv, v[3] * inv};
    orow[lane] = o0;
    if (has1) {
        float4 o1 = {v[4] * inv, v[5] * inv, v[6] * inv, v[7] * inv};
        orow[64 + lane] = o1;
    }
}

extern "C" void kernel_launch(void* const* d_in, const int* in_sizes, int n_in,
                              void* d_out, int out_size, void* d_ws, size_t ws_size,
                              hipStream_t stream) {
    const float* state  = (const float*)d_in[0];
    const float* dloc   = (const float*)d_in[1];
    const float* noise  = (const float*)d_in[2];
    const float* gu     = (const float*)d_in[3];
    const float* payoff = (const float*)d_in[4];
    const float* adj    = (const float*)d_in[5];
    const float* g1w    = (const float*)d_in[6];
    const float* g1b    = (const float*)d_in[7];
    const float* g2w    = (const float*)d_in[8];
    const float* g2b    = (const float*)d_in[9];
    const float* gamma  = (const float*)d_in[10];
    const float* beta   = (const float*)d_in[11];
    const float* aw     = (const float*)d_in[12];
    const float* av     = (const float*)d_in[13];
    float* out = (float*)d_out;

    float* ws     = (float*)d_ws;
    float* y1     = ws;           // 16000
    float* y2     = ws + 16000;   // 8000
    float* part1  = ws + 24000;   // 500*500 = 250000
    float* part2  = ws + 274000;  // 4*25000 = 100000
    float* logits = ws + 374000;  // 25000   (total 399000 floats = 1.6 MB)

    k1_xw<<<T_, 256, 0, stream>>>(state, payoff, noise, g1w, y1);
    k2_adj_fused<<<T_, 256, 0, stream>>>(adj, y1, g1b, gamma, beta, g2w, y2);
    k3_adj2_aw<<<T_, 256, 0, stream>>>(adj, y2, g2b, gamma, beta, aw, part1);
    k4_logits_part<<<dim3(R_, 8), 256, 0, stream>>>(dloc, av, part1, part2);
    k4_reduce<<<(R_ * T_ + 255) / 256, 256, 0, stream>>>(part2, logits);
    k7_softmax<<<(NS_ * R_) / 4, 256, 0, stream>>>(
        (const float4*)gu, (const float4*)logits, (float4*)out);
}

// Round 6
// 71.840 us; speedup vs baseline: 3.7119x; 1.0235x over previous
//
#include <hip/hip_runtime.h>

#define T_ 500
#define R_ 50
#define NS_ 1000
#define H1_ 32
#define H2_ 16
#define NEG_ 0.2f

typedef float vf4 __attribute__((ext_vector_type(4)));

__device__ __forceinline__ float lrelu(float x) { return x >= 0.f ? x : NEG_ * x; }

// One block per t: y1[t][c] = sum_f x[t][f] * gc1_w[f][c],  x=[state(2)|payoff row(500)|noise(2)]
__global__ __launch_bounds__(256) void k1_xw(const float* __restrict__ state,
                                             const float* __restrict__ payoff,
                                             const float* __restrict__ noise,
                                             const float* __restrict__ w,
                                             float* __restrict__ y1) {
    __shared__ float xs[504];
    __shared__ float red[8][H1_];
    int t = blockIdx.x, tid = threadIdx.x;
    for (int u = tid; u < T_; u += 256) xs[2 + u] = payoff[t * T_ + u];
    if (tid == 0) {
        xs[0] = state[t * 2];     xs[1] = state[t * 2 + 1];
        xs[502] = noise[t * 2];   xs[503] = noise[t * 2 + 1];
    }
    __syncthreads();
    int c = tid & 31, kg = tid >> 5;   // 8 k-groups x 32 channels
    float acc = 0.f;
#pragma unroll 7
    for (int f = kg; f < 504; f += 8) acc += xs[f] * w[f * H1_ + c];
    red[kg][c] = acc;
    __syncthreads();
    if (tid < H1_) {
        float a = 0.f;
#pragma unroll
        for (int s = 0; s < 8; ++s) a += red[s][tid];
        y1[t * H1_ + tid] = a;
    }
}

// One block per t: h1row = lrelu(bn(adj[t]@y1 + b)); y2[t][c2] = h1row @ g2w
__global__ __launch_bounds__(256) void k2_adj_fused(const float* __restrict__ adj,
                                                    const float* __restrict__ y1,
                                                    const float* __restrict__ b,
                                                    const float* __restrict__ gamma,
                                                    const float* __restrict__ beta,
                                                    const float* __restrict__ w2,
                                                    float* __restrict__ y2) {
    __shared__ float arow[T_];
    __shared__ float red[8][H1_];
    __shared__ float h1row[H1_];
    int t = blockIdx.x, tid = threadIdx.x;
    for (int u = tid; u < T_; u += 256) arow[u] = adj[t * T_ + u];
    __syncthreads();
    int c = tid & 31, kg = tid >> 5;
    float acc = 0.f;
#pragma unroll 4
    for (int u = kg; u < T_; u += 8) acc += arow[u] * y1[u * H1_ + c];
    red[kg][c] = acc;
    __syncthreads();
    if (tid < H1_) {
        float a = 0.f;
#pragma unroll
        for (int s = 0; s < 8; ++s) a += red[s][tid];
        h1row[tid] = lrelu((a + b[tid]) * gamma[t] + beta[t]);
    }
    __syncthreads();
    if (tid < H2_) {
        float a = 0.f;
#pragma unroll
        for (int cc = 0; cc < H1_; ++cc) a += h1row[cc] * w2[cc * H2_ + tid];
        y2[t * H2_ + tid] = a;
    }
}

// One block per t: xfrow = lrelu(bn(adj[t]@y2 + b2)); part1[t][j] = xfrow @ aw[t*16..t*16+16)
__global__ __launch_bounds__(256) void k3_adj2_aw(const float* __restrict__ adj,
                                                  const float* __restrict__ y2,
                                                  const float* __restrict__ b2,
                                                  const float* __restrict__ gamma,
                                                  const float* __restrict__ beta,
                                                  const float* __restrict__ aw,
                                                  float* __restrict__ part1) {
    __shared__ float arow[T_];
    __shared__ float red[16][H2_];
    __shared__ float xfr[H2_];
    int t = blockIdx.x, tid = threadIdx.x;
    for (int u = tid; u < T_; u += 256) arow[u] = adj[t * T_ + u];
    __syncthreads();
    int c2 = tid & 15, kg = tid >> 4;  // 16 k-groups x 16 channels
    float acc = 0.f;
#pragma unroll 4
    for (int u = kg; u < T_; u += 16) acc += arow[u] * y2[u * H2_ + c2];
    red[kg][c2] = acc;
    __syncthreads();
    if (tid < H2_) {
        float a = 0.f;
#pragma unroll
        for (int s = 0; s < 16; ++s) a += red[s][tid];
        xfr[tid] = lrelu((a + b2[tid]) * gamma[t] + beta[t]);
    }
    __syncthreads();
    float acc0 = 0.f, acc1 = 0.f;
#pragma unroll
    for (int c = 0; c < H2_; ++c) {
        float xv = xfr[c];
        const float* awr = aw + (t * H2_ + c) * T_;
        acc0 += xv * awr[tid];
        if (tid < T_ - 256) acc1 += xv * awr[256 + tid];
    }
    part1[t * T_ + tid] = acc0;
    if (tid < T_ - 256) part1[t * T_ + 256 + tid] = acc1;
}

// Block (r, y=q*2+jb): partial logits over t-quarter q, j-half jb.
// part2[q][r*T+j] = sum_{t in q} dloc[r][t]*av[t][j] + part1[t][j]
__global__ __launch_bounds__(256) void k4_logits_part(const float* __restrict__ dloc,
                                                      const float* __restrict__ av,
                                                      const float* __restrict__ part1,
                                                      float* __restrict__ part2) {
    int r = blockIdx.x;
    int jb = blockIdx.y & 1, q = blockIdx.y >> 1;
    __shared__ float drow[125];
    int tid = threadIdx.x;
    int t0 = q * 125;
    if (tid < 125) drow[tid] = dloc[r * T_ + t0 + tid];
    __syncthreads();
    if (tid >= 250) return;
    int j = jb * 250 + tid;
    float acc = 0.f;
#pragma unroll 5
    for (int i = 0; i < 125; ++i) {
        int t = t0 + i;
        acc += drow[i] * av[t * T_ + j] + part1[t * T_ + j];
    }
    part2[q * (R_ * T_) + r * T_ + j] = acc;
}

// elog[x] = exp(sum_q part2[q][x])   (exp folded here; row softmax later divides it out)
__global__ __launch_bounds__(256) void k4_reduce_exp(const float* __restrict__ part2,
                                                     float* __restrict__ elog) {
    int gid = blockIdx.x * 256 + threadIdx.x;
    if (gid >= R_ * T_) return;
    float v = part2[gid] + part2[R_ * T_ + gid] +
              part2[2 * R_ * T_ + gid] + part2[3 * R_ * T_ + gid];
    elog[gid] = __expf(v);
}

// One wave per row. softmax_j(logits_j - log(-log u_j)) = elog_j * rcp(-log2 u_j) / rowsum
// (the ln2 factor from using log2 is per-element-constant and cancels in the normalization)
__global__ __launch_bounds__(256) void k7_softmax(const float4* __restrict__ gu,
                                                  const float4* __restrict__ elog,
                                                  float* __restrict__ out) {
    int wave = threadIdx.x >> 6;
    int lane = threadIdx.x & 63;
    int row = blockIdx.x * 4 + wave;  // < 50000
    int r = row % R_;
    const float4* grow = gu + row * 125;
    const float4* erow = elog + r * 125;
    bool has1 = lane < 61;

    float4 g0 = grow[lane];
    float4 e0 = erow[lane];
    float4 g1, e1;
    if (has1) {
        g1 = grow[64 + lane];
        e1 = erow[64 + lane];
    }
    float p[8];
    p[0] = e0.x * __builtin_amdgcn_rcpf(-__log2f(g0.x));
    p[1] = e0.y * __builtin_amdgcn_rcpf(-__log2f(g0.y));
    p[2] = e0.z * __builtin_amdgcn_rcpf(-__log2f(g0.z));
    p[3] = e0.w * __builtin_amdgcn_rcpf(-__log2f(g0.w));
    if (has1) {
        p[4] = e1.x * __builtin_amdgcn_rcpf(-__log2f(g1.x));
        p[5] = e1.y * __builtin_amdgcn_rcpf(-__log2f(g1.y));
        p[6] = e1.z * __builtin_amdgcn_rcpf(-__log2f(g1.z));
        p[7] = e1.w * __builtin_amdgcn_rcpf(-__log2f(g1.w));
    } else {
        p[4] = p[5] = p[6] = p[7] = 0.f;
    }
    float s = ((p[0] + p[1]) + (p[2] + p[3])) + ((p[4] + p[5]) + (p[6] + p[7]));
#pragma unroll
    for (int off = 32; off > 0; off >>= 1) s += __shfl_xor(s, off);
    float inv = __builtin_amdgcn_rcpf(s);

    vf4* orow = (vf4*)(out + row * T_);
    vf4 o0 = {p[0] * inv, p[1] * inv, p[2] * inv, p[3] * inv};
    __builtin_nontemporal_store(o0, orow + lane);
    if (has1) {
        vf4 o1 = {p[4] * inv, p[5] * inv, p[6] * inv, p[7] * inv};
        __builtin_nontemporal_store(o1, orow + 64 + lane);
    }
}

extern "C" void kernel_launch(void* const* d_in, const int* in_sizes, int n_in,
                              void* d_out, int out_size, void* d_ws, size_t ws_size,
                              hipStream_t stream) {
    const float* state  = (const float*)d_in[0];
    const float* dloc   = (const float*)d_in[1];
    const float* noise  = (const float*)d_in[2];
    const float* gu     = (const float*)d_in[3];
    const float* payoff = (const float*)d_in[4];
    const float* adj    = (const float*)d_in[5];
    const float* g1w    = (const float*)d_in[6];
    const float* g1b    = (const float*)d_in[7];
    const float* g2w    = (const float*)d_in[8];
    const float* g2b    = (const float*)d_in[9];
    const float* gamma  = (const float*)d_in[10];
    const float* beta   = (const float*)d_in[11];
    const float* aw     = (const float*)d_in[12];
    const float* av     = (const float*)d_in[13];
    float* out = (float*)d_out;

    float* ws     = (float*)d_ws;
    float* y1     = ws;           // 16000
    float* y2     = ws + 16000;   // 8000
    float* part1  = ws + 24000;   // 500*500 = 250000
    float* part2  = ws + 274000;  // 4*25000 = 100000
    float* elog   = ws + 374000;  // 25000   (total 399000 floats = 1.6 MB)

    k1_xw<<<T_, 256, 0, stream>>>(state, payoff, noise, g1w, y1);
    k2_adj_fused<<<T_, 256, 0, stream>>>(adj, y1, g1b, gamma, beta, g2w, y2);
    k3_adj2_aw<<<T_, 256, 0, stream>>>(adj, y2, g2b, gamma, beta, aw, part1);
    k4_logits_part<<<dim3(R_, 8), 256, 0, stream>>>(dloc, av, part1, part2);
    k4_reduce_exp<<<(R_ * T_ + 255) / 256, 256, 0, stream>>>(part2, elog);
    k7_softmax<<<(NS_ * R_) / 4, 256, 0, stream>>>(
        (const float4*)gu, (const float4*)elog, (float*)out);
}